// Round 19
// baseline (449.904 us; speedup 1.0000x reference)
//
#include <hip/hip_runtime.h>

typedef __attribute__((ext_vector_type(8))) short bf16x8;
typedef __attribute__((ext_vector_type(4))) float f32x4;

__device__ __forceinline__ unsigned short f2bf(float f){
  unsigned int u = __builtin_bit_cast(unsigned int, f);
  u += 0x7fffu + ((u >> 16) & 1u);          // RTN-even
  return (unsigned short)(u >> 16);
}
__device__ __forceinline__ float bf_lo(unsigned int v){
  return __builtin_bit_cast(float, v << 16);
}
__device__ __forceinline__ float bf_hi(unsigned int v){
  return __builtin_bit_cast(float, v & 0xffff0000u);
}
__device__ __forceinline__ float lrelu(float x){ return x > 0.f ? x : 0.2f * x; }

#define GLOAD_LDS16(g, l) \
  __builtin_amdgcn_global_load_lds((const __attribute__((address_space(1))) unsigned int*)(g), \
                                   (__attribute__((address_space(3))) unsigned int*)(l), 16, 0, 0)

// ---------------- Kernel I: zero deg + W (f32 [k][c]) -> bf16 W^T [c][136] ---
__global__ __launch_bounds__(256) void k_init(const float* __restrict__ W,
                                              unsigned short* __restrict__ WbfT,
                                              int4* __restrict__ deg4, int n4){
  int i = blockIdx.x * 256 + threadIdx.x;
  if (i < n4){ int4 z; z.x=0; z.y=0; z.z=0; z.w=0; deg4[i] = z; }
  if (i < 128*128){
    int c = i & 127, k = i >> 7;
    WbfT[c * 136 + k] = f2bf(W[k * 128 + c]);
  }
}

// ------- Kernel A: fused h = x@W + dst histogram -----------------------------
// KEY CHANGE vs R18: NO x LDS staging. Lane's B-fragment is 8 consecutive
// floats of one x-row -> loaded DIRECTLY into registers (2xf32x4), 2-slice
// reg double-buffer, compiler-pipelined. LDS = Wt only (34.8KB) -> 3 blocks/CU
// at 3 waves/SIMD (launch_bounds(256,3)); 12 waves/CU each with 8KB in flight.
__global__ __launch_bounds__(256, 3) void k_gemm_hist(
    const float* __restrict__ x, const unsigned short* __restrict__ WbfT,
    const float* __restrict__ attS, const float* __restrict__ attD,
    unsigned short* __restrict__ h, float* __restrict__ aS, float* __restrict__ aD,
    int N, int nslices, int nbGemm,
    const int* __restrict__ dstA, int E, int* __restrict__ deg)
{
  __shared__ unsigned short Wt[128][136];     // 34816 B
  int tid = threadIdx.x;

  if ((int)blockIdx.x >= nbGemm){
    // ---- histogram part (never reaches __syncthreads; per-block uniform) ----
    int nb = (int)gridDim.x - nbGemm;
    int bid = (int)blockIdx.x - nbGemm;
    int t0 = bid * 256 + tid;
    int stride = nb * 256;
    int E4 = E >> 2;
    const int4* d4 = (const int4*)dstA;
    for (int i = t0; i < E4; i += stride){
      int4 d = d4[i];
      atomicAdd(&deg[d.x], 1);
      atomicAdd(&deg[d.y], 1);
      atomicAdd(&deg[d.z], 1);
      atomicAdd(&deg[d.w], 1);
    }
    for (int e = (E & ~3) + t0; e < E; e += stride) atomicAdd(&deg[dstA[e]], 1);
    return;
  }

  // ---- gemm part ----
  const char* wsrc = (const char*)WbfT;
  #pragma unroll
  for (int it = 0; it < 9; ++it){
    int i = it * 256 + tid;
    if (i < 2176) GLOAD_LDS16(wsrc + (size_t)i * 16, ((char*)Wt) + i * 16);
  }
  __syncthreads();   // once; loop below has no block-wide sync

  int wv = tid >> 6, lane = tid & 63;
  int lrow = lane & 15, lgrp = lane >> 4;

  int slice  = (int)blockIdx.x * 4 + wv;
  int stride = nbGemm * 4;

  // load slice s's per-lane fragment data directly into registers
  auto LOADS = [&](f32x4* v, int s){
    if (s >= nslices) s = nslices - 1;
    int r = s * 16 + lrow; if (r >= N) r = N - 1;
    const float* xp = x + (size_t)r * 128 + lgrp * 8;
    #pragma unroll
    for (int kt = 0; kt < 4; ++kt){
      v[kt*2]     = *(const f32x4*)(xp + kt * 32);
      v[kt*2 + 1] = *(const f32x4*)(xp + kt * 32 + 4);
    }
  };

  auto COMP = [&](const f32x4* v, int s){
    if (s >= nslices) return;               // wave-uniform guard
    bf16x8 af[4];
    #pragma unroll
    for (int kt = 0; kt < 4; ++kt){
      bf16x8 a;
      #pragma unroll
      for (int j = 0; j < 4; ++j){
        a[j]   = (short)f2bf(v[kt*2][j]);
        a[4+j] = (short)f2bf(v[kt*2+1][j]);
      }
      af[kt] = a;
    }

    f32x4 acc[8];
    #pragma unroll
    for (int ct = 0; ct < 8; ++ct){ acc[ct][0]=0.f; acc[ct][1]=0.f; acc[ct][2]=0.f; acc[ct][3]=0.f; }
    #pragma unroll
    for (int kt = 0; kt < 4; ++kt){
      #pragma unroll
      for (int ct = 0; ct < 8; ++ct){
        bf16x8 bw = *(const bf16x8*)&Wt[ct*16 + lrow][kt*32 + lgrp*8];
        acc[ct] = __builtin_amdgcn_mfma_f32_16x16x32_bf16(bw, af[kt], acc[ct], 0, 0, 0);
      }
    }

    int row = s * 16 + lrow;
    float ps[4] = {0.f,0.f,0.f,0.f}, pd[4] = {0.f,0.f,0.f,0.f};
    #pragma unroll
    for (int ct = 0; ct < 8; ++ct){
      int hh = ct >> 1;
      f32x4 s4 = *(const f32x4*)(attS + ct*16 + lgrp*4);
      f32x4 d4 = *(const f32x4*)(attD + ct*16 + lgrp*4);
      #pragma unroll
      for (int g = 0; g < 4; ++g){
        ps[hh] += acc[ct][g] * s4[g];
        pd[hh] += acc[ct][g] * d4[g];
      }
    }
    #pragma unroll
    for (int hh = 0; hh < 4; ++hh){
      ps[hh] += __shfl_xor(ps[hh], 16, 64);
      ps[hh] += __shfl_xor(ps[hh], 32, 64);
      pd[hh] += __shfl_xor(pd[hh], 16, 64);
      pd[hh] += __shfl_xor(pd[hh], 32, 64);
    }
    if (lgrp == 0 && row < N){
      f32x4 vs, vd;
      #pragma unroll
      for (int hh = 0; hh < 4; ++hh){ vs[hh] = ps[hh]; vd[hh] = pd[hh]; }
      *(f32x4*)(aS + (size_t)row * 4) = vs;
      *(f32x4*)(aD + (size_t)row * 4) = vd;
    }
    if (row < N){
      unsigned short* hp = h + (size_t)row * 128 + lgrp * 4;
      #pragma unroll
      for (int ct = 0; ct < 8; ++ct){
        unsigned int u0 = (unsigned int)f2bf(acc[ct][0])
                        | ((unsigned int)f2bf(acc[ct][1]) << 16);
        unsigned int u1 = (unsigned int)f2bf(acc[ct][2])
                        | ((unsigned int)f2bf(acc[ct][3]) << 16);
        uint2 u; u.x = u0; u.y = u1;
        *(uint2*)(hp + ct * 16) = u;
      }
    }
  };

  f32x4 vA[8], vB[8];
  LOADS(vA, slice);
  for (int s = slice; s < nslices; s += 2 * stride){
    LOADS(vB, s + stride);            // prefetch B under A's compute
    COMP(vA, s);
    LOADS(vA, s + 2 * stride);        // prefetch next A under B's compute
    COMP(vB, s + stride);
  }
}

// ---------------- CSR scan ----------------
__global__ __launch_bounds__(256) void k_chunksum(const int* __restrict__ deg, int N,
                                                  int* __restrict__ bsum){
  __shared__ int sm[256];
  int tid = threadIdx.x;
  int base = blockIdx.x * 2048 + tid * 8;
  int s = 0;
  #pragma unroll
  for (int j = 0; j < 8; ++j) s += (base + j < N) ? deg[base + j] : 0;
  sm[tid] = s; __syncthreads();
  for (int off = 128; off > 0; off >>= 1){
    if (tid < off) sm[tid] += sm[tid + off];
    __syncthreads();
  }
  if (tid == 0) bsum[blockIdx.x] = sm[0];
}

__global__ __launch_bounds__(256) void k_scansums(int* __restrict__ bsum, int nb){
  __shared__ int sm[256];
  int tid = threadIdx.x;
  int carry = 0;
  for (int base = 0; base < nb; base += 256){
    int v = (base + tid < nb) ? bsum[base + tid] : 0;
    sm[tid] = v; __syncthreads();
    for (int off = 1; off < 256; off <<= 1){
      int t = (tid >= off) ? sm[tid - off] : 0;
      __syncthreads();
      sm[tid] += t;
      __syncthreads();
    }
    int incl = sm[tid];
    int total = sm[255];
    __syncthreads();
    if (base + tid < nb) bsum[base + tid] = carry + incl - v;
    carry += total;
  }
}

__global__ __launch_bounds__(256) void k_scanfinal(const int* __restrict__ deg,
    const int* __restrict__ bsum, int N, int E,
    int* __restrict__ rowptr, int* __restrict__ cursor){
  __shared__ int sm[256];
  int tid = threadIdx.x;
  int base = blockIdx.x * 2048 + tid * 8;
  int v[8];
  #pragma unroll
  for (int j = 0; j < 8; ++j) v[j] = (base + j < N) ? deg[base + j] : 0;
  int t = 0;
  #pragma unroll
  for (int j = 0; j < 8; ++j){ int x_ = v[j]; v[j] = t; t += x_; }
  sm[tid] = t; __syncthreads();
  for (int off = 1; off < 256; off <<= 1){
    int u = (tid >= off) ? sm[tid - off] : 0;
    __syncthreads();
    sm[tid] += u;
    __syncthreads();
  }
  int excl = sm[tid] - t;
  int off0 = bsum[blockIdx.x] + excl;
  #pragma unroll
  for (int j = 0; j < 8; ++j){
    if (base + j < N){
      int val = off0 + v[j];
      rowptr[base + j] = val;
      cursor[base + j] = val;
    }
  }
  if (blockIdx.x == 0 && tid == 0) rowptr[N] = E;
}

// ------- Kernel S: scatter combined edge record (ONE 32B slot per edge) -----
__global__ __launch_bounds__(256) void k_scatter(const int* __restrict__ src,
    const int* __restrict__ dst, int E, int* __restrict__ cursor,
    const float* __restrict__ aS, const float* __restrict__ aD,
    float* __restrict__ eb){
  int e = blockIdx.x * 256 + threadIdx.x;
  if (e < E){
    int s = src[e], d = dst[e];
    int p = atomicAdd(&cursor[d], 1);
    f32x4 as = *(const f32x4*)(aS + (size_t)s * 4);
    f32x4 ad = *(const f32x4*)(aD + (size_t)d * 4);
    f32x4 w;
    #pragma unroll
    for (int hh = 0; hh < 4; ++hh) w[hh] = __expf(lrelu(as[hh] + ad[hh]));
    float* rec = eb + (size_t)p * 8;
    *(f32x4*)rec = w;
    rec[4] = __builtin_bit_cast(float, s);
  }
}

// ---------------- Kernel C: gather from edge records + fc head --------------
__global__ __launch_bounds__(256) void k_aggr(
    const uint4* __restrict__ h4, const float* __restrict__ aS,
    const float* __restrict__ aD, const int* __restrict__ rowptr,
    const float* __restrict__ eb, const float* __restrict__ bias,
    const float* __restrict__ fcw, const float* __restrict__ fcb,
    float* __restrict__ out, int N)
{
  int lane = threadIdx.x & 63;
  int l16  = lane & 15;
  int node = ((int)blockIdx.x * 256 + (int)threadIdx.x) >> 4;
  if (node >= N) return;
  int head = l16 >> 2;

  float wself = __expf(lrelu(aS[node * 4 + head] + aD[node * 4 + head]));
  float wsum  = wself;

  float acc[8];
  {
    uint4 hv = h4[node * 16 + l16];
    acc[0] = wself * bf_lo(hv.x);  acc[1] = wself * bf_hi(hv.x);
    acc[2] = wself * bf_lo(hv.y);  acc[3] = wself * bf_hi(hv.y);
    acc[4] = wself * bf_lo(hv.z);  acc[5] = wself * bf_hi(hv.z);
    acc[6] = wself * bf_lo(hv.w);  acc[7] = wself * bf_hi(hv.w);
  }

  int rb = rowptr[node], re = rowptr[node + 1];
  for (int j = rb; j < re; j += 4){
    int i1 = (j + 1 < re) ? j + 1 : j;
    int i2 = (j + 2 < re) ? j + 2 : j;
    int i3 = (j + 3 < re) ? j + 3 : j;
    float m1 = (j + 1 < re) ? 1.f : 0.f;
    float m2 = (j + 2 < re) ? 1.f : 0.f;
    float m3 = (j + 3 < re) ? 1.f : 0.f;
    float w0 = eb[(size_t)j  * 8 + head];
    float w1 = eb[(size_t)i1 * 8 + head] * m1;
    float w2 = eb[(size_t)i2 * 8 + head] * m2;
    float w3 = eb[(size_t)i3 * 8 + head] * m3;
    int s0 = __builtin_bit_cast(int, eb[(size_t)j  * 8 + 4]);
    int s1 = __builtin_bit_cast(int, eb[(size_t)i1 * 8 + 4]);
    int s2 = __builtin_bit_cast(int, eb[(size_t)i2 * 8 + 4]);
    int s3 = __builtin_bit_cast(int, eb[(size_t)i3 * 8 + 4]);
    uint4 v0 = h4[(size_t)s0 * 16 + l16];
    uint4 v1 = h4[(size_t)s1 * 16 + l16];
    uint4 v2 = h4[(size_t)s2 * 16 + l16];
    uint4 v3 = h4[(size_t)s3 * 16 + l16];
    wsum += w0 + w1 + w2 + w3;
    acc[0] += w0*bf_lo(v0.x) + w1*bf_lo(v1.x) + w2*bf_lo(v2.x) + w3*bf_lo(v3.x);
    acc[1] += w0*bf_hi(v0.x) + w1*bf_hi(v1.x) + w2*bf_hi(v2.x) + w3*bf_hi(v3.x);
    acc[2] += w0*bf_lo(v0.y) + w1*bf_lo(v1.y) + w2*bf_lo(v2.y) + w3*bf_lo(v3.y);
    acc[3] += w0*bf_hi(v0.y) + w1*bf_hi(v1.y) + w2*bf_hi(v2.y) + w3*bf_hi(v3.y);
    acc[4] += w0*bf_lo(v0.z) + w1*bf_lo(v1.z) + w2*bf_lo(v2.z) + w3*bf_lo(v3.z);
    acc[5] += w0*bf_hi(v0.z) + w1*bf_hi(v1.z) + w2*bf_hi(v2.z) + w3*bf_hi(v3.z);
    acc[6] += w0*bf_lo(v0.w) + w1*bf_lo(v1.w) + w2*bf_lo(v2.w) + w3*bf_lo(v3.w);
    acc[7] += w0*bf_hi(v0.w) + w1*bf_hi(v1.w) + w2*bf_hi(v2.w) + w3*bf_hi(v3.w);
  }

  float inv = 1.f / wsum;
  const float* bp = bias + l16 * 8;
  const float* fp = fcw  + l16 * 8;
  f32x4 b0 = *(const f32x4*)bp,      b1 = *(const f32x4*)(bp + 4);
  f32x4 f0 = *(const f32x4*)fp,      f1 = *(const f32x4*)(fp + 4);
  float p = 0.f;
  p += fmaxf(acc[0]*inv + b0[0], 0.f) * f0[0];
  p += fmaxf(acc[1]*inv + b0[1], 0.f) * f0[1];
  p += fmaxf(acc[2]*inv + b0[2], 0.f) * f0[2];
  p += fmaxf(acc[3]*inv + b0[3], 0.f) * f0[3];
  p += fmaxf(acc[4]*inv + b1[0], 0.f) * f1[0];
  p += fmaxf(acc[5]*inv + b1[1], 0.f) * f1[1];
  p += fmaxf(acc[6]*inv + b1[2], 0.f) * f1[2];
  p += fmaxf(acc[7]*inv + b1[3], 0.f) * f1[3];
  #pragma unroll
  for (int m = 1; m < 16; m <<= 1) p += __shfl_xor(p, m, 64);
  if (l16 == 0) out[node] = 1.f / (1.f + __expf(-(p + fcb[0])));
}

extern "C" void kernel_launch(void* const* d_in, const int* in_sizes, int n_in,
                              void* d_out, int out_size, void* d_ws, size_t ws_size,
                              hipStream_t stream) {
  const float* x    = (const float*)d_in[0];
  const int*   ei   = (const int*)  d_in[1];
  const float* W    = (const float*)d_in[2];
  const float* attS = (const float*)d_in[3];
  const float* attD = (const float*)d_in[4];
  const float* bias = (const float*)d_in[5];
  const float* fcw  = (const float*)d_in[6];
  const float* fcb  = (const float*)d_in[7];

  int N = in_sizes[0] / 128;
  int E = in_sizes[1] / 2;
  const int* srcA = ei;
  const int* dstA = ei + E;

  char* ws = (char*)d_ws;
  size_t off = 0;
  auto alloc = [&](size_t bytes) -> void* {
    void* p = ws + off;
    off += (bytes + 255) & ~(size_t)255;
    return p;
  };
  unsigned short* h  = (unsigned short*)alloc((size_t)N * 128 * 2);
  float* aS   = (float*)alloc((size_t)N * 4 * 4);
  float* aD   = (float*)alloc((size_t)N * 4 * 4);
  int* deg    = (int*)alloc((size_t)N * 4);
  int* rowptr = (int*)alloc(((size_t)N + 1) * 4);
  int* cursor = (int*)alloc((size_t)N * 4);
  float* eb   = (float*)alloc((size_t)E * 32 + 64);
  int* bsum   = (int*)alloc(4096);
  unsigned short* WbfT = (unsigned short*)alloc(128 * 136 * 2);

  int n4 = (N + 3) / 4;
  int ninit = (n4 > 16384) ? n4 : 16384;
  k_init<<<(ninit + 255) / 256, 256, 0, stream>>>(W, WbfT, (int4*)deg, n4);
  int nslices = (N + 15) / 16;
  int nbGemm = 768, nbHist = 256;
  k_gemm_hist<<<nbGemm + nbHist, 256, 0, stream>>>(x, WbfT, attS, attD, h, aS, aD,
                                                   N, nslices, nbGemm, dstA, E, deg);
  int nb = (N + 2047) / 2048;
  k_chunksum<<<nb, 256, 0, stream>>>(deg, N, bsum);
  k_scansums<<<1, 256, 0, stream>>>(bsum, nb);
  k_scanfinal<<<nb, 256, 0, stream>>>(deg, bsum, N, E, rowptr, cursor);
  k_scatter<<<(E + 255) / 256, 256, 0, stream>>>(srcA, dstA, E, cursor, aS, aD, eb);
  k_aggr<<<(N + 15) / 16, 256, 0, stream>>>((const uint4*)h, aS, aD, rowptr, eb,
                                            bias, fcw, fcb, (float*)d_out, N);
}

// Round 20
// 352.829 us; speedup vs baseline: 1.2751x; 1.2751x over previous
//
#include <hip/hip_runtime.h>

typedef __attribute__((ext_vector_type(8))) short bf16x8;
typedef __attribute__((ext_vector_type(4))) float f32x4;

__device__ __forceinline__ unsigned short f2bf(float f){
  unsigned int u = __builtin_bit_cast(unsigned int, f);
  u += 0x7fffu + ((u >> 16) & 1u);          // RTN-even
  return (unsigned short)(u >> 16);
}
__device__ __forceinline__ float bf_lo(unsigned int v){
  return __builtin_bit_cast(float, v << 16);
}
__device__ __forceinline__ float bf_hi(unsigned int v){
  return __builtin_bit_cast(float, v & 0xffff0000u);
}
__device__ __forceinline__ float lrelu(float x){ return x > 0.f ? x : 0.2f * x; }

#define GLOAD_LDS16(g, l) \
  __builtin_amdgcn_global_load_lds((const __attribute__((address_space(1))) unsigned int*)(g), \
                                   (__attribute__((address_space(3))) unsigned int*)(l), 16, 0, 0)

// ---------------- Kernel I: zero deg + W (f32 [k][c]) -> bf16 W^T [c][136] ---
__global__ __launch_bounds__(256) void k_init(const float* __restrict__ W,
                                              unsigned short* __restrict__ WbfT,
                                              int4* __restrict__ deg4, int n4){
  int i = blockIdx.x * 256 + threadIdx.x;
  if (i < n4){ int4 z; z.x=0; z.y=0; z.z=0; z.w=0; deg4[i] = z; }
  if (i < 128*128){
    int c = i & 127, k = i >> 7;
    WbfT[c * 136 + k] = f2bf(W[k * 128 + c]);
  }
}

// ------- Kernel A: fused h = x@W (W-in-registers gemm, DMA-staged x) + hist -
// R18 structure (best measured: DMA staging preserves full-line access + L3
// residency; reg/direct-load variants over-fetch 2x — R10/R19).
// Grid = 512 = EXACTLY 2 blocks/CU so ALL blocks co-resident: 480 gemm +
// 32 hist -> hist truly overlaps instead of running in the tail (R18 issue).
__global__ __launch_bounds__(256, 2) void k_gemm_hist(
    const float* __restrict__ x, const unsigned short* __restrict__ WbfT,
    const float* __restrict__ attS, const float* __restrict__ attD,
    unsigned short* __restrict__ h, float* __restrict__ aS, float* __restrict__ aD,
    int N, int nslices, int nbGemm,
    const int* __restrict__ dstA, int E, int* __restrict__ deg)
{
  __shared__ float xbuf[4][2][16*128];        // 64KB (unused by hist blocks)
  int tid = threadIdx.x;

  if ((int)blockIdx.x >= nbGemm){
    // ---- histogram part ----
    int nb = (int)gridDim.x - nbGemm;
    int bid = (int)blockIdx.x - nbGemm;
    int t0 = bid * 256 + tid;
    int stride = nb * 256;
    int E4 = E >> 2;
    const int4* d4 = (const int4*)dstA;
    for (int i = t0; i < E4; i += stride){
      int4 d = d4[i];
      atomicAdd(&deg[d.x], 1);
      atomicAdd(&deg[d.y], 1);
      atomicAdd(&deg[d.z], 1);
      atomicAdd(&deg[d.w], 1);
    }
    for (int e = (E & ~3) + t0; e < E; e += stride) atomicAdd(&deg[dstA[e]], 1);
    return;
  }

  // ---- gemm part ----
  int wv = tid >> 6, lane = tid & 63;
  int lrow = lane & 15, lgrp = lane >> 4;

  bf16x8 wf[4][8];
  #pragma unroll
  for (int kt = 0; kt < 4; ++kt)
    #pragma unroll
    for (int ct = 0; ct < 8; ++ct)
      wf[kt][ct] = *(const bf16x8*)(WbfT + (ct*16 + lrow) * 136 + kt*32 + lgrp*8);

  int slice  = (int)blockIdx.x * 4 + wv;
  int stride = nbGemm * 4;

  auto STAGE = [&](int s, int b){
    if (s >= nslices) s = nslices - 1;
    char* dst0 = (char*)&xbuf[wv][b][0];
    #pragma unroll
    for (int k = 0; k < 8; ++k){
      int c = k * 64 + lane;
      int r = c >> 5, j = c & 31;
      int gr = s * 16 + r; if (gr >= N) gr = N - 1;
      const char* src = (const char*)(x + (size_t)gr * 128) + ((j ^ (r & 7)) << 4);
      GLOAD_LDS16(src, dst0 + k * 1024);
    }
  };

  STAGE(slice, 0);
  int bi = 0;

  for (int s = slice; s < nslices; s += stride){
    STAGE(s + stride, bi ^ 1);
    asm volatile("s_waitcnt vmcnt(8)" ::: "memory");   // buf bi complete

    const f32x4* xb = (const f32x4*)&xbuf[wv][bi][0];
    bf16x8 af[4];
    #pragma unroll
    for (int kt = 0; kt < 4; ++kt){
      int j0 = kt * 8 + lgrp * 2;
      f32x4 lo = xb[lrow * 32 + ( j0      ^ (lrow & 7))];
      f32x4 hi = xb[lrow * 32 + ((j0 + 1) ^ (lrow & 7))];
      bf16x8 a;
      #pragma unroll
      for (int j = 0; j < 4; ++j){
        a[j]   = (short)f2bf(lo[j]);
        a[4+j] = (short)f2bf(hi[j]);
      }
      af[kt] = a;
    }

    f32x4 acc[8];
    #pragma unroll
    for (int ct = 0; ct < 8; ++ct){ acc[ct][0]=0.f; acc[ct][1]=0.f; acc[ct][2]=0.f; acc[ct][3]=0.f; }
    #pragma unroll
    for (int kt = 0; kt < 4; ++kt){
      #pragma unroll
      for (int ct = 0; ct < 8; ++ct){
        acc[ct] = __builtin_amdgcn_mfma_f32_16x16x32_bf16(wf[kt][ct], af[kt], acc[ct], 0, 0, 0);
      }
    }

    int row = s * 16 + lrow;
    float ps[4] = {0.f,0.f,0.f,0.f}, pd[4] = {0.f,0.f,0.f,0.f};
    #pragma unroll
    for (int ct = 0; ct < 8; ++ct){
      int hh = ct >> 1;
      f32x4 s4 = *(const f32x4*)(attS + ct*16 + lgrp*4);
      f32x4 d4 = *(const f32x4*)(attD + ct*16 + lgrp*4);
      #pragma unroll
      for (int g = 0; g < 4; ++g){
        ps[hh] += acc[ct][g] * s4[g];
        pd[hh] += acc[ct][g] * d4[g];
      }
    }
    #pragma unroll
    for (int hh = 0; hh < 4; ++hh){
      ps[hh] += __shfl_xor(ps[hh], 16, 64);
      ps[hh] += __shfl_xor(ps[hh], 32, 64);
      pd[hh] += __shfl_xor(pd[hh], 16, 64);
      pd[hh] += __shfl_xor(pd[hh], 32, 64);
    }
    if (lgrp == 0 && row < N){
      f32x4 vs, vd;
      #pragma unroll
      for (int hh = 0; hh < 4; ++hh){ vs[hh] = ps[hh]; vd[hh] = pd[hh]; }
      *(f32x4*)(aS + (size_t)row * 4) = vs;
      *(f32x4*)(aD + (size_t)row * 4) = vd;
    }
    if (row < N){
      unsigned short* hp = h + (size_t)row * 128 + lgrp * 4;
      #pragma unroll
      for (int ct = 0; ct < 8; ++ct){
        unsigned int u0 = (unsigned int)f2bf(acc[ct][0])
                        | ((unsigned int)f2bf(acc[ct][1]) << 16);
        unsigned int u1 = (unsigned int)f2bf(acc[ct][2])
                        | ((unsigned int)f2bf(acc[ct][3]) << 16);
        uint2 u; u.x = u0; u.y = u1;
        *(uint2*)(hp + ct * 16) = u;
      }
    }
    bi ^= 1;
  }
}

// ---------------- CSR scan ----------------
__global__ __launch_bounds__(256) void k_chunksum(const int* __restrict__ deg, int N,
                                                  int* __restrict__ bsum){
  __shared__ int sm[256];
  int tid = threadIdx.x;
  int base = blockIdx.x * 2048 + tid * 8;
  int s = 0;
  #pragma unroll
  for (int j = 0; j < 8; ++j) s += (base + j < N) ? deg[base + j] : 0;
  sm[tid] = s; __syncthreads();
  for (int off = 128; off > 0; off >>= 1){
    if (tid < off) sm[tid] += sm[tid + off];
    __syncthreads();
  }
  if (tid == 0) bsum[blockIdx.x] = sm[0];
}

__global__ __launch_bounds__(256) void k_scansums(int* __restrict__ bsum, int nb){
  __shared__ int sm[256];
  int tid = threadIdx.x;
  int carry = 0;
  for (int base = 0; base < nb; base += 256){
    int v = (base + tid < nb) ? bsum[base + tid] : 0;
    sm[tid] = v; __syncthreads();
    for (int off = 1; off < 256; off <<= 1){
      int t = (tid >= off) ? sm[tid - off] : 0;
      __syncthreads();
      sm[tid] += t;
      __syncthreads();
    }
    int incl = sm[tid];
    int total = sm[255];
    __syncthreads();
    if (base + tid < nb) bsum[base + tid] = carry + incl - v;
    carry += total;
  }
}

__global__ __launch_bounds__(256) void k_scanfinal(const int* __restrict__ deg,
    const int* __restrict__ bsum, int N, int E,
    int* __restrict__ rowptr, int* __restrict__ cursor){
  __shared__ int sm[256];
  int tid = threadIdx.x;
  int base = blockIdx.x * 2048 + tid * 8;
  int v[8];
  #pragma unroll
  for (int j = 0; j < 8; ++j) v[j] = (base + j < N) ? deg[base + j] : 0;
  int t = 0;
  #pragma unroll
  for (int j = 0; j < 8; ++j){ int x_ = v[j]; v[j] = t; t += x_; }
  sm[tid] = t; __syncthreads();
  for (int off = 1; off < 256; off <<= 1){
    int u = (tid >= off) ? sm[tid - off] : 0;
    __syncthreads();
    sm[tid] += u;
    __syncthreads();
  }
  int excl = sm[tid] - t;
  int off0 = bsum[blockIdx.x] + excl;
  #pragma unroll
  for (int j = 0; j < 8; ++j){
    if (base + j < N){
      int val = off0 + v[j];
      rowptr[base + j] = val;
      cursor[base + j] = val;
    }
  }
  if (blockIdx.x == 0 && tid == 0) rowptr[N] = E;
}

// ------- Kernel S: scatter combined edge record (ONE 32B slot per edge) -----
__global__ __launch_bounds__(256) void k_scatter(const int* __restrict__ src,
    const int* __restrict__ dst, int E, int* __restrict__ cursor,
    const float* __restrict__ aS, const float* __restrict__ aD,
    float* __restrict__ eb){
  int e = blockIdx.x * 256 + threadIdx.x;
  if (e < E){
    int s = src[e], d = dst[e];
    int p = atomicAdd(&cursor[d], 1);
    f32x4 as = *(const f32x4*)(aS + (size_t)s * 4);
    f32x4 ad = *(const f32x4*)(aD + (size_t)d * 4);
    f32x4 w;
    #pragma unroll
    for (int hh = 0; hh < 4; ++hh) w[hh] = __expf(lrelu(as[hh] + ad[hh]));
    float* rec = eb + (size_t)p * 8;
    *(f32x4*)rec = w;
    rec[4] = __builtin_bit_cast(float, s);
  }
}

// ---------------- Kernel C: gather from edge records + fc head --------------
__global__ __launch_bounds__(256) void k_aggr(
    const uint4* __restrict__ h4, const float* __restrict__ aS,
    const float* __restrict__ aD, const int* __restrict__ rowptr,
    const float* __restrict__ eb, const float* __restrict__ bias,
    const float* __restrict__ fcw, const float* __restrict__ fcb,
    float* __restrict__ out, int N)
{
  int lane = threadIdx.x & 63;
  int l16  = lane & 15;
  int node = ((int)blockIdx.x * 256 + (int)threadIdx.x) >> 4;
  if (node >= N) return;
  int head = l16 >> 2;

  float wself = __expf(lrelu(aS[node * 4 + head] + aD[node * 4 + head]));
  float wsum  = wself;

  float acc[8];
  {
    uint4 hv = h4[node * 16 + l16];
    acc[0] = wself * bf_lo(hv.x);  acc[1] = wself * bf_hi(hv.x);
    acc[2] = wself * bf_lo(hv.y);  acc[3] = wself * bf_hi(hv.y);
    acc[4] = wself * bf_lo(hv.z);  acc[5] = wself * bf_hi(hv.z);
    acc[6] = wself * bf_lo(hv.w);  acc[7] = wself * bf_hi(hv.w);
  }

  int rb = rowptr[node], re = rowptr[node + 1];
  for (int j = rb; j < re; j += 4){
    int i1 = (j + 1 < re) ? j + 1 : j;
    int i2 = (j + 2 < re) ? j + 2 : j;
    int i3 = (j + 3 < re) ? j + 3 : j;
    float m1 = (j + 1 < re) ? 1.f : 0.f;
    float m2 = (j + 2 < re) ? 1.f : 0.f;
    float m3 = (j + 3 < re) ? 1.f : 0.f;
    float w0 = eb[(size_t)j  * 8 + head];
    float w1 = eb[(size_t)i1 * 8 + head] * m1;
    float w2 = eb[(size_t)i2 * 8 + head] * m2;
    float w3 = eb[(size_t)i3 * 8 + head] * m3;
    int s0 = __builtin_bit_cast(int, eb[(size_t)j  * 8 + 4]);
    int s1 = __builtin_bit_cast(int, eb[(size_t)i1 * 8 + 4]);
    int s2 = __builtin_bit_cast(int, eb[(size_t)i2 * 8 + 4]);
    int s3 = __builtin_bit_cast(int, eb[(size_t)i3 * 8 + 4]);
    uint4 v0 = h4[(size_t)s0 * 16 + l16];
    uint4 v1 = h4[(size_t)s1 * 16 + l16];
    uint4 v2 = h4[(size_t)s2 * 16 + l16];
    uint4 v3 = h4[(size_t)s3 * 16 + l16];
    wsum += w0 + w1 + w2 + w3;
    acc[0] += w0*bf_lo(v0.x) + w1*bf_lo(v1.x) + w2*bf_lo(v2.x) + w3*bf_lo(v3.x);
    acc[1] += w0*bf_hi(v0.x) + w1*bf_hi(v1.x) + w2*bf_hi(v2.x) + w3*bf_hi(v3.x);
    acc[2] += w0*bf_lo(v0.y) + w1*bf_lo(v1.y) + w2*bf_lo(v2.y) + w3*bf_lo(v3.y);
    acc[3] += w0*bf_hi(v0.y) + w1*bf_hi(v1.y) + w2*bf_hi(v2.y) + w3*bf_hi(v3.y);
    acc[4] += w0*bf_lo(v0.z) + w1*bf_lo(v1.z) + w2*bf_lo(v2.z) + w3*bf_lo(v3.z);
    acc[5] += w0*bf_hi(v0.z) + w1*bf_hi(v1.z) + w2*bf_hi(v2.z) + w3*bf_hi(v3.z);
    acc[6] += w0*bf_lo(v0.w) + w1*bf_lo(v1.w) + w2*bf_lo(v2.w) + w3*bf_lo(v3.w);
    acc[7] += w0*bf_hi(v0.w) + w1*bf_hi(v1.w) + w2*bf_hi(v2.w) + w3*bf_hi(v3.w);
  }

  float inv = 1.f / wsum;
  const float* bp = bias + l16 * 8;
  const float* fp = fcw  + l16 * 8;
  f32x4 b0 = *(const f32x4*)bp,      b1 = *(const f32x4*)(bp + 4);
  f32x4 f0 = *(const f32x4*)fp,      f1 = *(const f32x4*)(fp + 4);
  float p = 0.f;
  p += fmaxf(acc[0]*inv + b0[0], 0.f) * f0[0];
  p += fmaxf(acc[1]*inv + b0[1], 0.f) * f0[1];
  p += fmaxf(acc[2]*inv + b0[2], 0.f) * f0[2];
  p += fmaxf(acc[3]*inv + b0[3], 0.f) * f0[3];
  p += fmaxf(acc[4]*inv + b1[0], 0.f) * f1[0];
  p += fmaxf(acc[5]*inv + b1[1], 0.f) * f1[1];
  p += fmaxf(acc[6]*inv + b1[2], 0.f) * f1[2];
  p += fmaxf(acc[7]*inv + b1[3], 0.f) * f1[3];
  #pragma unroll
  for (int m = 1; m < 16; m <<= 1) p += __shfl_xor(p, m, 64);
  if (l16 == 0) out[node] = 1.f / (1.f + __expf(-(p + fcb[0])));
}

extern "C" void kernel_launch(void* const* d_in, const int* in_sizes, int n_in,
                              void* d_out, int out_size, void* d_ws, size_t ws_size,
                              hipStream_t stream) {
  const float* x    = (const float*)d_in[0];
  const int*   ei   = (const int*)  d_in[1];
  const float* W    = (const float*)d_in[2];
  const float* attS = (const float*)d_in[3];
  const float* attD = (const float*)d_in[4];
  const float* bias = (const float*)d_in[5];
  const float* fcw  = (const float*)d_in[6];
  const float* fcb  = (const float*)d_in[7];

  int N = in_sizes[0] / 128;
  int E = in_sizes[1] / 2;
  const int* srcA = ei;
  const int* dstA = ei + E;

  char* ws = (char*)d_ws;
  size_t off = 0;
  auto alloc = [&](size_t bytes) -> void* {
    void* p = ws + off;
    off += (bytes + 255) & ~(size_t)255;
    return p;
  };
  unsigned short* h  = (unsigned short*)alloc((size_t)N * 128 * 2);
  float* aS   = (float*)alloc((size_t)N * 4 * 4);
  float* aD   = (float*)alloc((size_t)N * 4 * 4);
  int* deg    = (int*)alloc((size_t)N * 4);
  int* rowptr = (int*)alloc(((size_t)N + 1) * 4);
  int* cursor = (int*)alloc((size_t)N * 4);
  float* eb   = (float*)alloc((size_t)E * 32 + 64);
  int* bsum   = (int*)alloc(4096);
  unsigned short* WbfT = (unsigned short*)alloc(128 * 136 * 2);

  int n4 = (N + 3) / 4;
  int ninit = (n4 > 16384) ? n4 : 16384;
  k_init<<<(ninit + 255) / 256, 256, 0, stream>>>(W, WbfT, (int4*)deg, n4);
  int nslices = (N + 15) / 16;
  int nbGemm = 480, nbHist = 32;   // total 512 = exactly 2 blocks/CU, all co-resident
  k_gemm_hist<<<nbGemm + nbHist, 256, 0, stream>>>(x, WbfT, attS, attD, h, aS, aD,
                                                   N, nslices, nbGemm, dstA, E, deg);
  int nb = (N + 2047) / 2048;
  k_chunksum<<<nb, 256, 0, stream>>>(deg, N, bsum);
  k_scansums<<<1, 256, 0, stream>>>(bsum, nb);
  k_scanfinal<<<nb, 256, 0, stream>>>(deg, bsum, N, E, rowptr, cursor);
  k_scatter<<<(E + 255) / 256, 256, 0, stream>>>(srcA, dstA, E, cursor, aS, aD, eb);
  k_aggr<<<(N + 15) / 16, 256, 0, stream>>>((const uint4*)h, aS, aD, rowptr, eb,
                                            bias, fcw, fcb, (float*)d_out, N);
}

// Round 21
// 327.148 us; speedup vs baseline: 1.3752x; 1.0785x over previous
//
#include <hip/hip_runtime.h>

typedef __attribute__((ext_vector_type(8))) short bf16x8;
typedef __attribute__((ext_vector_type(4))) float f32x4;

__device__ __forceinline__ unsigned short f2bf(float f){
  unsigned int u = __builtin_bit_cast(unsigned int, f);
  u += 0x7fffu + ((u >> 16) & 1u);          // RTN-even
  return (unsigned short)(u >> 16);
}
__device__ __forceinline__ float bf_lo(unsigned int v){
  return __builtin_bit_cast(float, v << 16);
}
__device__ __forceinline__ float bf_hi(unsigned int v){
  return __builtin_bit_cast(float, v & 0xffff0000u);
}
__device__ __forceinline__ float lrelu(float x){ return x > 0.f ? x : 0.2f * x; }

#define GLOAD_LDS16(g, l) \
  __builtin_amdgcn_global_load_lds((const __attribute__((address_space(1))) unsigned int*)(g), \
                                   (__attribute__((address_space(3))) unsigned int*)(l), 16, 0, 0)

// ---------------- Kernel I: zero deg + W (f32 [k][c]) -> bf16 W^T [c][136] ---
__global__ __launch_bounds__(256) void k_init(const float* __restrict__ W,
                                              unsigned short* __restrict__ WbfT,
                                              int4* __restrict__ deg4, int n4){
  int i = blockIdx.x * 256 + threadIdx.x;
  if (i < n4){ int4 z; z.x=0; z.y=0; z.z=0; z.w=0; deg4[i] = z; }
  if (i < 128*128){
    int c = i & 127, k = i >> 7;
    WbfT[c * 136 + k] = f2bf(W[k * 128 + c]);
  }
}

// ------- Kernel A: fused h = x@W (W-in-registers gemm, DMA-staged x) + hist -
// EXACT R18 config (best measured: 512 gemm + 256 hist, grid 768; hist runs
// full-width in the tail — R20 showed co-resident small-hist is worse).
__global__ __launch_bounds__(256, 2) void k_gemm_hist(
    const float* __restrict__ x, const unsigned short* __restrict__ WbfT,
    const float* __restrict__ attS, const float* __restrict__ attD,
    unsigned short* __restrict__ h, float* __restrict__ aS, float* __restrict__ aD,
    int N, int nslices, int nbGemm,
    const int* __restrict__ dstA, int E, int* __restrict__ deg)
{
  __shared__ float xbuf[4][2][16*128];        // 64KB (unused by hist blocks)
  int tid = threadIdx.x;

  if ((int)blockIdx.x >= nbGemm){
    // ---- histogram part ----
    int nb = (int)gridDim.x - nbGemm;
    int bid = (int)blockIdx.x - nbGemm;
    int t0 = bid * 256 + tid;
    int stride = nb * 256;
    int E4 = E >> 2;
    const int4* d4 = (const int4*)dstA;
    for (int i = t0; i < E4; i += stride){
      int4 d = d4[i];
      atomicAdd(&deg[d.x], 1);
      atomicAdd(&deg[d.y], 1);
      atomicAdd(&deg[d.z], 1);
      atomicAdd(&deg[d.w], 1);
    }
    for (int e = (E & ~3) + t0; e < E; e += stride) atomicAdd(&deg[dstA[e]], 1);
    return;
  }

  // ---- gemm part ----
  int wv = tid >> 6, lane = tid & 63;
  int lrow = lane & 15, lgrp = lane >> 4;

  bf16x8 wf[4][8];
  #pragma unroll
  for (int kt = 0; kt < 4; ++kt)
    #pragma unroll
    for (int ct = 0; ct < 8; ++ct)
      wf[kt][ct] = *(const bf16x8*)(WbfT + (ct*16 + lrow) * 136 + kt*32 + lgrp*8);

  int slice  = (int)blockIdx.x * 4 + wv;
  int stride = nbGemm * 4;

  auto STAGE = [&](int s, int b){
    if (s >= nslices) s = nslices - 1;
    char* dst0 = (char*)&xbuf[wv][b][0];
    #pragma unroll
    for (int k = 0; k < 8; ++k){
      int c = k * 64 + lane;
      int r = c >> 5, j = c & 31;
      int gr = s * 16 + r; if (gr >= N) gr = N - 1;
      const char* src = (const char*)(x + (size_t)gr * 128) + ((j ^ (r & 7)) << 4);
      GLOAD_LDS16(src, dst0 + k * 1024);
    }
  };

  STAGE(slice, 0);
  int bi = 0;

  for (int s = slice; s < nslices; s += stride){
    STAGE(s + stride, bi ^ 1);
    asm volatile("s_waitcnt vmcnt(8)" ::: "memory");   // buf bi complete

    const f32x4* xb = (const f32x4*)&xbuf[wv][bi][0];
    bf16x8 af[4];
    #pragma unroll
    for (int kt = 0; kt < 4; ++kt){
      int j0 = kt * 8 + lgrp * 2;
      f32x4 lo = xb[lrow * 32 + ( j0      ^ (lrow & 7))];
      f32x4 hi = xb[lrow * 32 + ((j0 + 1) ^ (lrow & 7))];
      bf16x8 a;
      #pragma unroll
      for (int j = 0; j < 4; ++j){
        a[j]   = (short)f2bf(lo[j]);
        a[4+j] = (short)f2bf(hi[j]);
      }
      af[kt] = a;
    }

    f32x4 acc[8];
    #pragma unroll
    for (int ct = 0; ct < 8; ++ct){ acc[ct][0]=0.f; acc[ct][1]=0.f; acc[ct][2]=0.f; acc[ct][3]=0.f; }
    #pragma unroll
    for (int kt = 0; kt < 4; ++kt){
      #pragma unroll
      for (int ct = 0; ct < 8; ++ct){
        acc[ct] = __builtin_amdgcn_mfma_f32_16x16x32_bf16(wf[kt][ct], af[kt], acc[ct], 0, 0, 0);
      }
    }

    int row = s * 16 + lrow;
    float ps[4] = {0.f,0.f,0.f,0.f}, pd[4] = {0.f,0.f,0.f,0.f};
    #pragma unroll
    for (int ct = 0; ct < 8; ++ct){
      int hh = ct >> 1;
      f32x4 s4 = *(const f32x4*)(attS + ct*16 + lgrp*4);
      f32x4 d4 = *(const f32x4*)(attD + ct*16 + lgrp*4);
      #pragma unroll
      for (int g = 0; g < 4; ++g){
        ps[hh] += acc[ct][g] * s4[g];
        pd[hh] += acc[ct][g] * d4[g];
      }
    }
    #pragma unroll
    for (int hh = 0; hh < 4; ++hh){
      ps[hh] += __shfl_xor(ps[hh], 16, 64);
      ps[hh] += __shfl_xor(ps[hh], 32, 64);
      pd[hh] += __shfl_xor(pd[hh], 16, 64);
      pd[hh] += __shfl_xor(pd[hh], 32, 64);
    }
    if (lgrp == 0 && row < N){
      f32x4 vs, vd;
      #pragma unroll
      for (int hh = 0; hh < 4; ++hh){ vs[hh] = ps[hh]; vd[hh] = pd[hh]; }
      *(f32x4*)(aS + (size_t)row * 4) = vs;
      *(f32x4*)(aD + (size_t)row * 4) = vd;
    }
    if (row < N){
      unsigned short* hp = h + (size_t)row * 128 + lgrp * 4;
      #pragma unroll
      for (int ct = 0; ct < 8; ++ct){
        unsigned int u0 = (unsigned int)f2bf(acc[ct][0])
                        | ((unsigned int)f2bf(acc[ct][1]) << 16);
        unsigned int u1 = (unsigned int)f2bf(acc[ct][2])
                        | ((unsigned int)f2bf(acc[ct][3]) << 16);
        uint2 u; u.x = u0; u.y = u1;
        *(uint2*)(hp + ct * 16) = u;
      }
    }
    bi ^= 1;
  }
}

// ---------------- CSR scan ----------------
__global__ __launch_bounds__(256) void k_chunksum(const int* __restrict__ deg, int N,
                                                  int* __restrict__ bsum){
  __shared__ int sm[256];
  int tid = threadIdx.x;
  int base = blockIdx.x * 2048 + tid * 8;
  int s = 0;
  #pragma unroll
  for (int j = 0; j < 8; ++j) s += (base + j < N) ? deg[base + j] : 0;
  sm[tid] = s; __syncthreads();
  for (int off = 128; off > 0; off >>= 1){
    if (tid < off) sm[tid] += sm[tid + off];
    __syncthreads();
  }
  if (tid == 0) bsum[blockIdx.x] = sm[0];
}

// Fused scansums+scanfinal (valid when nbsum <= 256): every block redundantly
// block-scans bsum in LDS, takes its own exclusive prefix, then applies its
// local 2048-element scan -> rowptr/cursor. Saves one launch + one bsum pass.
__global__ __launch_bounds__(256) void k_scanapply(const int* __restrict__ deg,
    const int* __restrict__ bsum, int nbsum, int N, int E,
    int* __restrict__ rowptr, int* __restrict__ cursor){
  __shared__ int sm[256];
  int tid = threadIdx.x;
  int bv = (tid < nbsum) ? bsum[tid] : 0;
  sm[tid] = bv; __syncthreads();
  for (int off = 1; off < 256; off <<= 1){
    int t = (tid >= off) ? sm[tid - off] : 0;
    __syncthreads();
    sm[tid] += t;
    __syncthreads();
  }
  int excl_b = (blockIdx.x == 0) ? 0 : sm[blockIdx.x - 1];
  __syncthreads();

  int base = blockIdx.x * 2048 + tid * 8;
  int v[8];
  #pragma unroll
  for (int j = 0; j < 8; ++j) v[j] = (base + j < N) ? deg[base + j] : 0;
  int t = 0;
  #pragma unroll
  for (int j = 0; j < 8; ++j){ int x_ = v[j]; v[j] = t; t += x_; }
  sm[tid] = t; __syncthreads();
  for (int off = 1; off < 256; off <<= 1){
    int u = (tid >= off) ? sm[tid - off] : 0;
    __syncthreads();
    sm[tid] += u;
    __syncthreads();
  }
  int excl = sm[tid] - t;
  int off0 = excl_b + excl;
  #pragma unroll
  for (int j = 0; j < 8; ++j){
    if (base + j < N){
      int val = off0 + v[j];
      rowptr[base + j] = val;
      cursor[base + j] = val;
    }
  }
  if (blockIdx.x == 0 && tid == 0) rowptr[N] = E;
}

// Fallback pair (used only if nbsum > 256; not expected at this problem size)
__global__ __launch_bounds__(256) void k_scansums(int* __restrict__ bsum, int nb){
  __shared__ int sm[256];
  int tid = threadIdx.x;
  int carry = 0;
  for (int base = 0; base < nb; base += 256){
    int v = (base + tid < nb) ? bsum[base + tid] : 0;
    sm[tid] = v; __syncthreads();
    for (int off = 1; off < 256; off <<= 1){
      int t = (tid >= off) ? sm[tid - off] : 0;
      __syncthreads();
      sm[tid] += t;
      __syncthreads();
    }
    int incl = sm[tid];
    int total = sm[255];
    __syncthreads();
    if (base + tid < nb) bsum[base + tid] = carry + incl - v;
    carry += total;
  }
}

__global__ __launch_bounds__(256) void k_scanfinal(const int* __restrict__ deg,
    const int* __restrict__ bsum, int N, int E,
    int* __restrict__ rowptr, int* __restrict__ cursor){
  __shared__ int sm[256];
  int tid = threadIdx.x;
  int base = blockIdx.x * 2048 + tid * 8;
  int v[8];
  #pragma unroll
  for (int j = 0; j < 8; ++j) v[j] = (base + j < N) ? deg[base + j] : 0;
  int t = 0;
  #pragma unroll
  for (int j = 0; j < 8; ++j){ int x_ = v[j]; v[j] = t; t += x_; }
  sm[tid] = t; __syncthreads();
  for (int off = 1; off < 256; off <<= 1){
    int u = (tid >= off) ? sm[tid - off] : 0;
    __syncthreads();
    sm[tid] += u;
    __syncthreads();
  }
  int excl = sm[tid] - t;
  int off0 = bsum[blockIdx.x] + excl;
  #pragma unroll
  for (int j = 0; j < 8; ++j){
    if (base + j < N){
      int val = off0 + v[j];
      rowptr[base + j] = val;
      cursor[base + j] = val;
    }
  }
  if (blockIdx.x == 0 && tid == 0) rowptr[N] = E;
}

// ------- Kernel S: scatter combined edge record (ONE 32B slot per edge) -----
__global__ __launch_bounds__(256) void k_scatter(const int* __restrict__ src,
    const int* __restrict__ dst, int E, int* __restrict__ cursor,
    const float* __restrict__ aS, const float* __restrict__ aD,
    float* __restrict__ eb){
  int e = blockIdx.x * 256 + threadIdx.x;
  if (e < E){
    int s = src[e], d = dst[e];
    int p = atomicAdd(&cursor[d], 1);
    f32x4 as = *(const f32x4*)(aS + (size_t)s * 4);
    f32x4 ad = *(const f32x4*)(aD + (size_t)d * 4);
    f32x4 w;
    #pragma unroll
    for (int hh = 0; hh < 4; ++hh) w[hh] = __expf(lrelu(as[hh] + ad[hh]));
    float* rec = eb + (size_t)p * 8;
    *(f32x4*)rec = w;
    rec[4] = __builtin_bit_cast(float, s);
  }
}

// ---------------- Kernel C: gather from edge records + fc head --------------
__global__ __launch_bounds__(256) void k_aggr(
    const uint4* __restrict__ h4, const float* __restrict__ aS,
    const float* __restrict__ aD, const int* __restrict__ rowptr,
    const float* __restrict__ eb, const float* __restrict__ bias,
    const float* __restrict__ fcw, const float* __restrict__ fcb,
    float* __restrict__ out, int N)
{
  int lane = threadIdx.x & 63;
  int l16  = lane & 15;
  int node = ((int)blockIdx.x * 256 + (int)threadIdx.x) >> 4;
  if (node >= N) return;
  int head = l16 >> 2;

  float wself = __expf(lrelu(aS[node * 4 + head] + aD[node * 4 + head]));
  float wsum  = wself;

  float acc[8];
  {
    uint4 hv = h4[node * 16 + l16];
    acc[0] = wself * bf_lo(hv.x);  acc[1] = wself * bf_hi(hv.x);
    acc[2] = wself * bf_lo(hv.y);  acc[3] = wself * bf_hi(hv.y);
    acc[4] = wself * bf_lo(hv.z);  acc[5] = wself * bf_hi(hv.z);
    acc[6] = wself * bf_lo(hv.w);  acc[7] = wself * bf_hi(hv.w);
  }

  int rb = rowptr[node], re = rowptr[node + 1];
  for (int j = rb; j < re; j += 4){
    int i1 = (j + 1 < re) ? j + 1 : j;
    int i2 = (j + 2 < re) ? j + 2 : j;
    int i3 = (j + 3 < re) ? j + 3 : j;
    float m1 = (j + 1 < re) ? 1.f : 0.f;
    float m2 = (j + 2 < re) ? 1.f : 0.f;
    float m3 = (j + 3 < re) ? 1.f : 0.f;
    float w0 = eb[(size_t)j  * 8 + head];
    float w1 = eb[(size_t)i1 * 8 + head] * m1;
    float w2 = eb[(size_t)i2 * 8 + head] * m2;
    float w3 = eb[(size_t)i3 * 8 + head] * m3;
    int s0 = __builtin_bit_cast(int, eb[(size_t)j  * 8 + 4]);
    int s1 = __builtin_bit_cast(int, eb[(size_t)i1 * 8 + 4]);
    int s2 = __builtin_bit_cast(int, eb[(size_t)i2 * 8 + 4]);
    int s3 = __builtin_bit_cast(int, eb[(size_t)i3 * 8 + 4]);
    uint4 v0 = h4[(size_t)s0 * 16 + l16];
    uint4 v1 = h4[(size_t)s1 * 16 + l16];
    uint4 v2 = h4[(size_t)s2 * 16 + l16];
    uint4 v3 = h4[(size_t)s3 * 16 + l16];
    wsum += w0 + w1 + w2 + w3;
    acc[0] += w0*bf_lo(v0.x) + w1*bf_lo(v1.x) + w2*bf_lo(v2.x) + w3*bf_lo(v3.x);
    acc[1] += w0*bf_hi(v0.x) + w1*bf_hi(v1.x) + w2*bf_hi(v2.x) + w3*bf_hi(v3.x);
    acc[2] += w0*bf_lo(v0.y) + w1*bf_lo(v1.y) + w2*bf_lo(v2.y) + w3*bf_lo(v3.y);
    acc[3] += w0*bf_hi(v0.y) + w1*bf_hi(v1.y) + w2*bf_hi(v2.y) + w3*bf_hi(v3.y);
    acc[4] += w0*bf_lo(v0.z) + w1*bf_lo(v1.z) + w2*bf_lo(v2.z) + w3*bf_lo(v3.z);
    acc[5] += w0*bf_hi(v0.z) + w1*bf_hi(v1.z) + w2*bf_hi(v2.z) + w3*bf_hi(v3.z);
    acc[6] += w0*bf_lo(v0.w) + w1*bf_lo(v1.w) + w2*bf_lo(v2.w) + w3*bf_lo(v3.w);
    acc[7] += w0*bf_hi(v0.w) + w1*bf_hi(v1.w) + w2*bf_hi(v2.w) + w3*bf_hi(v3.w);
  }

  float inv = 1.f / wsum;
  const float* bp = bias + l16 * 8;
  const float* fp = fcw  + l16 * 8;
  f32x4 b0 = *(const f32x4*)bp,      b1 = *(const f32x4*)(bp + 4);
  f32x4 f0 = *(const f32x4*)fp,      f1 = *(const f32x4*)(fp + 4);
  float p = 0.f;
  p += fmaxf(acc[0]*inv + b0[0], 0.f) * f0[0];
  p += fmaxf(acc[1]*inv + b0[1], 0.f) * f0[1];
  p += fmaxf(acc[2]*inv + b0[2], 0.f) * f0[2];
  p += fmaxf(acc[3]*inv + b0[3], 0.f) * f0[3];
  p += fmaxf(acc[4]*inv + b1[0], 0.f) * f1[0];
  p += fmaxf(acc[5]*inv + b1[1], 0.f) * f1[1];
  p += fmaxf(acc[6]*inv + b1[2], 0.f) * f1[2];
  p += fmaxf(acc[7]*inv + b1[3], 0.f) * f1[3];
  #pragma unroll
  for (int m = 1; m < 16; m <<= 1) p += __shfl_xor(p, m, 64);
  if (l16 == 0) out[node] = 1.f / (1.f + __expf(-(p + fcb[0])));
}

extern "C" void kernel_launch(void* const* d_in, const int* in_sizes, int n_in,
                              void* d_out, int out_size, void* d_ws, size_t ws_size,
                              hipStream_t stream) {
  const float* x    = (const float*)d_in[0];
  const int*   ei   = (const int*)  d_in[1];
  const float* W    = (const float*)d_in[2];
  const float* attS = (const float*)d_in[3];
  const float* attD = (const float*)d_in[4];
  const float* bias = (const float*)d_in[5];
  const float* fcw  = (const float*)d_in[6];
  const float* fcb  = (const float*)d_in[7];

  int N = in_sizes[0] / 128;
  int E = in_sizes[1] / 2;
  const int* srcA = ei;
  const int* dstA = ei + E;

  char* ws = (char*)d_ws;
  size_t off = 0;
  auto alloc = [&](size_t bytes) -> void* {
    void* p = ws + off;
    off += (bytes + 255) & ~(size_t)255;
    return p;
  };
  unsigned short* h  = (unsigned short*)alloc((size_t)N * 128 * 2);
  float* aS   = (float*)alloc((size_t)N * 4 * 4);
  float* aD   = (float*)alloc((size_t)N * 4 * 4);
  int* deg    = (int*)alloc((size_t)N * 4);
  int* rowptr = (int*)alloc(((size_t)N + 1) * 4);
  int* cursor = (int*)alloc((size_t)N * 4);
  float* eb   = (float*)alloc((size_t)E * 32 + 64);
  int* bsum   = (int*)alloc(4096);
  unsigned short* WbfT = (unsigned short*)alloc(128 * 136 * 2);

  int n4 = (N + 3) / 4;
  int ninit = (n4 > 16384) ? n4 : 16384;
  k_init<<<(ninit + 255) / 256, 256, 0, stream>>>(W, WbfT, (int4*)deg, n4);
  int nslices = (N + 15) / 16;
  int nbGemm = 512, nbHist = 256;   // R18 config (best measured)
  k_gemm_hist<<<nbGemm + nbHist, 256, 0, stream>>>(x, WbfT, attS, attD, h, aS, aD,
                                                   N, nslices, nbGemm, dstA, E, deg);
  int nb = (N + 2047) / 2048;
  k_chunksum<<<nb, 256, 0, stream>>>(deg, N, bsum);
  if (nb <= 256){
    k_scanapply<<<nb, 256, 0, stream>>>(deg, bsum, nb, N, E, rowptr, cursor);
  } else {
    k_scansums<<<1, 256, 0, stream>>>(bsum, nb);
    k_scanfinal<<<nb, 256, 0, stream>>>(deg, bsum, N, E, rowptr, cursor);
  }
  k_scatter<<<(E + 255) / 256, 256, 0, stream>>>(srcA, dstA, E, cursor, aS, aD, eb);
  k_aggr<<<(N + 15) / 16, 256, 0, stream>>>((const uint4*)h, aS, aD, rowptr, eb,
                                            bias, fcw, fcb, (float*)d_out, N);
}

// Round 24
// 326.715 us; speedup vs baseline: 1.3771x; 1.0013x over previous
//
#include <hip/hip_runtime.h>

typedef __attribute__((ext_vector_type(8))) short bf16x8;
typedef __attribute__((ext_vector_type(4))) float f32x4;

__device__ __forceinline__ unsigned short f2bf(float f){
  unsigned int u = __builtin_bit_cast(unsigned int, f);
  u += 0x7fffu + ((u >> 16) & 1u);          // RTN-even
  return (unsigned short)(u >> 16);
}
__device__ __forceinline__ float bf_lo(unsigned int v){
  return __builtin_bit_cast(float, v << 16);
}
__device__ __forceinline__ float bf_hi(unsigned int v){
  return __builtin_bit_cast(float, v & 0xffff0000u);
}
__device__ __forceinline__ float lrelu(float x){ return x > 0.f ? x : 0.2f * x; }

#define GLOAD_LDS16(g, l) \
  __builtin_amdgcn_global_load_lds((const __attribute__((address_space(1))) unsigned int*)(g), \
                                   (__attribute__((address_space(3))) unsigned int*)(l), 16, 0, 0)

// ---------------- Kernel I: zero deg + W (f32 [k][c]) -> bf16 W^T [c][136] ---
__global__ __launch_bounds__(256) void k_init(const float* __restrict__ W,
                                              unsigned short* __restrict__ WbfT,
                                              int4* __restrict__ deg4, int n4){
  int i = blockIdx.x * 256 + threadIdx.x;
  if (i < n4){ int4 z; z.x=0; z.y=0; z.z=0; z.w=0; deg4[i] = z; }
  if (i < 128*128){
    int c = i & 127, k = i >> 7;
    WbfT[c * 136 + k] = f2bf(W[k * 128 + c]);
  }
}

// ------- Kernel A: fused h = x@W (W-in-registers gemm, DMA-staged x) + hist -
// Best measured config (R18/R21): 512 gemm + 256 hist blocks, grid 768.
// NOTE (R22/R23 lesson): aggregation must stay in h-space — softmax weights
// are per-head, and h's channels are head-partitioned so per-channel
// weighting is correct; pre-W (x-space) aggregation needs 4x state/work.
__global__ __launch_bounds__(256, 2) void k_gemm_hist(
    const float* __restrict__ x, const unsigned short* __restrict__ WbfT,
    const float* __restrict__ attS, const float* __restrict__ attD,
    unsigned short* __restrict__ h, float* __restrict__ aS, float* __restrict__ aD,
    int N, int nslices, int nbGemm,
    const int* __restrict__ dstA, int E, int* __restrict__ deg)
{
  __shared__ float xbuf[4][2][16*128];        // 64KB (unused by hist blocks)
  int tid = threadIdx.x;

  if ((int)blockIdx.x >= nbGemm){
    // ---- histogram part ----
    int nb = (int)gridDim.x - nbGemm;
    int bid = (int)blockIdx.x - nbGemm;
    int t0 = bid * 256 + tid;
    int stride = nb * 256;
    int E4 = E >> 2;
    const int4* d4 = (const int4*)dstA;
    for (int i = t0; i < E4; i += stride){
      int4 d = d4[i];
      atomicAdd(&deg[d.x], 1);
      atomicAdd(&deg[d.y], 1);
      atomicAdd(&deg[d.z], 1);
      atomicAdd(&deg[d.w], 1);
    }
    for (int e = (E & ~3) + t0; e < E; e += stride) atomicAdd(&deg[dstA[e]], 1);
    return;
  }

  // ---- gemm part ----
  int wv = tid >> 6, lane = tid & 63;
  int lrow = lane & 15, lgrp = lane >> 4;

  bf16x8 wf[4][8];
  #pragma unroll
  for (int kt = 0; kt < 4; ++kt)
    #pragma unroll
    for (int ct = 0; ct < 8; ++ct)
      wf[kt][ct] = *(const bf16x8*)(WbfT + (ct*16 + lrow) * 136 + kt*32 + lgrp*8);

  int slice  = (int)blockIdx.x * 4 + wv;
  int stride = nbGemm * 4;

  auto STAGE = [&](int s, int b){
    if (s >= nslices) s = nslices - 1;
    char* dst0 = (char*)&xbuf[wv][b][0];
    #pragma unroll
    for (int k = 0; k < 8; ++k){
      int c = k * 64 + lane;
      int r = c >> 5, j = c & 31;
      int gr = s * 16 + r; if (gr >= N) gr = N - 1;
      const char* src = (const char*)(x + (size_t)gr * 128) + ((j ^ (r & 7)) << 4);
      GLOAD_LDS16(src, dst0 + k * 1024);
    }
  };

  STAGE(slice, 0);
  int bi = 0;

  for (int s = slice; s < nslices; s += stride){
    STAGE(s + stride, bi ^ 1);
    asm volatile("s_waitcnt vmcnt(8)" ::: "memory");   // buf bi complete

    const f32x4* xb = (const f32x4*)&xbuf[wv][bi][0];
    bf16x8 af[4];
    #pragma unroll
    for (int kt = 0; kt < 4; ++kt){
      int j0 = kt * 8 + lgrp * 2;
      f32x4 lo = xb[lrow * 32 + ( j0      ^ (lrow & 7))];
      f32x4 hi = xb[lrow * 32 + ((j0 + 1) ^ (lrow & 7))];
      bf16x8 a;
      #pragma unroll
      for (int j = 0; j < 4; ++j){
        a[j]   = (short)f2bf(lo[j]);
        a[4+j] = (short)f2bf(hi[j]);
      }
      af[kt] = a;
    }

    f32x4 acc[8];
    #pragma unroll
    for (int ct = 0; ct < 8; ++ct){ acc[ct][0]=0.f; acc[ct][1]=0.f; acc[ct][2]=0.f; acc[ct][3]=0.f; }
    #pragma unroll
    for (int kt = 0; kt < 4; ++kt){
      #pragma unroll
      for (int ct = 0; ct < 8; ++ct){
        acc[ct] = __builtin_amdgcn_mfma_f32_16x16x32_bf16(wf[kt][ct], af[kt], acc[ct], 0, 0, 0);
      }
    }

    int row = s * 16 + lrow;
    float ps[4] = {0.f,0.f,0.f,0.f}, pd[4] = {0.f,0.f,0.f,0.f};
    #pragma unroll
    for (int ct = 0; ct < 8; ++ct){
      int hh = ct >> 1;
      f32x4 s4 = *(const f32x4*)(attS + ct*16 + lgrp*4);
      f32x4 d4 = *(const f32x4*)(attD + ct*16 + lgrp*4);
      #pragma unroll
      for (int g = 0; g < 4; ++g){
        ps[hh] += acc[ct][g] * s4[g];
        pd[hh] += acc[ct][g] * d4[g];
      }
    }
    #pragma unroll
    for (int hh = 0; hh < 4; ++hh){
      ps[hh] += __shfl_xor(ps[hh], 16, 64);
      ps[hh] += __shfl_xor(ps[hh], 32, 64);
      pd[hh] += __shfl_xor(pd[hh], 16, 64);
      pd[hh] += __shfl_xor(pd[hh], 32, 64);
    }
    if (lgrp == 0 && row < N){
      f32x4 vs, vd;
      #pragma unroll
      for (int hh = 0; hh < 4; ++hh){ vs[hh] = ps[hh]; vd[hh] = pd[hh]; }
      *(f32x4*)(aS + (size_t)row * 4) = vs;
      *(f32x4*)(aD + (size_t)row * 4) = vd;
    }
    if (row < N){
      unsigned short* hp = h + (size_t)row * 128 + lgrp * 4;
      #pragma unroll
      for (int ct = 0; ct < 8; ++ct){
        unsigned int u0 = (unsigned int)f2bf(acc[ct][0])
                        | ((unsigned int)f2bf(acc[ct][1]) << 16);
        unsigned int u1 = (unsigned int)f2bf(acc[ct][2])
                        | ((unsigned int)f2bf(acc[ct][3]) << 16);
        uint2 u; u.x = u0; u.y = u1;
        *(uint2*)(hp + ct * 16) = u;
      }
    }
    bi ^= 1;
  }
}

// ---------------- CSR scan ----------------
__global__ __launch_bounds__(256) void k_chunksum(const int* __restrict__ deg, int N,
                                                  int* __restrict__ bsum){
  __shared__ int sm[256];
  int tid = threadIdx.x;
  int base = blockIdx.x * 2048 + tid * 8;
  int s = 0;
  #pragma unroll
  for (int j = 0; j < 8; ++j) s += (base + j < N) ? deg[base + j] : 0;
  sm[tid] = s; __syncthreads();
  for (int off = 128; off > 0; off >>= 1){
    if (tid < off) sm[tid] += sm[tid + off];
    __syncthreads();
  }
  if (tid == 0) bsum[blockIdx.x] = sm[0];
}

__global__ __launch_bounds__(256) void k_scanapply(const int* __restrict__ deg,
    const int* __restrict__ bsum, int nbsum, int N, int E,
    int* __restrict__ rowptr, int* __restrict__ cursor){
  __shared__ int sm[256];
  int tid = threadIdx.x;
  int bv = (tid < nbsum) ? bsum[tid] : 0;
  sm[tid] = bv; __syncthreads();
  for (int off = 1; off < 256; off <<= 1){
    int t = (tid >= off) ? sm[tid - off] : 0;
    __syncthreads();
    sm[tid] += t;
    __syncthreads();
  }
  int excl_b = (blockIdx.x == 0) ? 0 : sm[blockIdx.x - 1];
  __syncthreads();

  int base = blockIdx.x * 2048 + tid * 8;
  int v[8];
  #pragma unroll
  for (int j = 0; j < 8; ++j) v[j] = (base + j < N) ? deg[base + j] : 0;
  int t = 0;
  #pragma unroll
  for (int j = 0; j < 8; ++j){ int x_ = v[j]; v[j] = t; t += x_; }
  sm[tid] = t; __syncthreads();
  for (int off = 1; off < 256; off <<= 1){
    int u = (tid >= off) ? sm[tid - off] : 0;
    __syncthreads();
    sm[tid] += u;
    __syncthreads();
  }
  int excl = sm[tid] - t;
  int off0 = excl_b + excl;
  #pragma unroll
  for (int j = 0; j < 8; ++j){
    if (base + j < N){
      int val = off0 + v[j];
      rowptr[base + j] = val;
      cursor[base + j] = val;
    }
  }
  if (blockIdx.x == 0 && tid == 0) rowptr[N] = E;
}

__global__ __launch_bounds__(256) void k_scansums(int* __restrict__ bsum, int nb){
  __shared__ int sm[256];
  int tid = threadIdx.x;
  int carry = 0;
  for (int base = 0; base < nb; base += 256){
    int v = (base + tid < nb) ? bsum[base + tid] : 0;
    sm[tid] = v; __syncthreads();
    for (int off = 1; off < 256; off <<= 1){
      int t = (tid >= off) ? sm[tid - off] : 0;
      __syncthreads();
      sm[tid] += t;
      __syncthreads();
    }
    int incl = sm[tid];
    int total = sm[255];
    __syncthreads();
    if (base + tid < nb) bsum[base + tid] = carry + incl - v;
    carry += total;
  }
}

__global__ __launch_bounds__(256) void k_scanfinal(const int* __restrict__ deg,
    const int* __restrict__ bsum, int N, int E,
    int* __restrict__ rowptr, int* __restrict__ cursor){
  __shared__ int sm[256];
  int tid = threadIdx.x;
  int base = blockIdx.x * 2048 + tid * 8;
  int v[8];
  #pragma unroll
  for (int j = 0; j < 8; ++j) v[j] = (base + j < N) ? deg[base + j] : 0;
  int t = 0;
  #pragma unroll
  for (int j = 0; j < 8; ++j){ int x_ = v[j]; v[j] = t; t += x_; }
  sm[tid] = t; __syncthreads();
  for (int off = 1; off < 256; off <<= 1){
    int u = (tid >= off) ? sm[tid - off] : 0;
    __syncthreads();
    sm[tid] += u;
    __syncthreads();
  }
  int excl = sm[tid] - t;
  int off0 = bsum[blockIdx.x] + excl;
  #pragma unroll
  for (int j = 0; j < 8; ++j){
    if (base + j < N){
      int val = off0 + v[j];
      rowptr[base + j] = val;
      cursor[base + j] = val;
    }
  }
  if (blockIdx.x == 0 && tid == 0) rowptr[N] = E;
}

// ------- Kernel S: scatter combined edge record (ONE 32B slot per edge) -----
__global__ __launch_bounds__(256) void k_scatter(const int* __restrict__ src,
    const int* __restrict__ dst, int E, int* __restrict__ cursor,
    const float* __restrict__ aS, const float* __restrict__ aD,
    float* __restrict__ eb){
  int e = blockIdx.x * 256 + threadIdx.x;
  if (e < E){
    int s = src[e], d = dst[e];
    int p = atomicAdd(&cursor[d], 1);
    f32x4 as = *(const f32x4*)(aS + (size_t)s * 4);
    f32x4 ad = *(const f32x4*)(aD + (size_t)d * 4);
    f32x4 w;
    #pragma unroll
    for (int hh = 0; hh < 4; ++hh) w[hh] = __expf(lrelu(as[hh] + ad[hh]));
    float* rec = eb + (size_t)p * 8;
    *(f32x4*)rec = w;
    rec[4] = __builtin_bit_cast(float, s);
  }
}

// ---------------- Kernel C: gather from edge records + fc head --------------
__global__ __launch_bounds__(256) void k_aggr(
    const uint4* __restrict__ h4, const float* __restrict__ aS,
    const float* __restrict__ aD, const int* __restrict__ rowptr,
    const float* __restrict__ eb, const float* __restrict__ bias,
    const float* __restrict__ fcw, const float* __restrict__ fcb,
    float* __restrict__ out, int N)
{
  int lane = threadIdx.x & 63;
  int l16  = lane & 15;
  int node = ((int)blockIdx.x * 256 + (int)threadIdx.x) >> 4;
  if (node >= N) return;
  int head = l16 >> 2;

  float wself = __expf(lrelu(aS[node * 4 + head] + aD[node * 4 + head]));
  float wsum  = wself;

  float acc[8];
  {
    uint4 hv = h4[node * 16 + l16];
    acc[0] = wself * bf_lo(hv.x);  acc[1] = wself * bf_hi(hv.x);
    acc[2] = wself * bf_lo(hv.y);  acc[3] = wself * bf_hi(hv.y);
    acc[4] = wself * bf_lo(hv.z);  acc[5] = wself * bf_hi(hv.z);
    acc[6] = wself * bf_lo(hv.w);  acc[7] = wself * bf_hi(hv.w);
  }

  int rb = rowptr[node], re = rowptr[node + 1];
  for (int j = rb; j < re; j += 4){
    int i1 = (j + 1 < re) ? j + 1 : j;
    int i2 = (j + 2 < re) ? j + 2 : j;
    int i3 = (j + 3 < re) ? j + 3 : j;
    float m1 = (j + 1 < re) ? 1.f : 0.f;
    float m2 = (j + 2 < re) ? 1.f : 0.f;
    float m3 = (j + 3 < re) ? 1.f : 0.f;
    float w0 = eb[(size_t)j  * 8 + head];
    float w1 = eb[(size_t)i1 * 8 + head] * m1;
    float w2 = eb[(size_t)i2 * 8 + head] * m2;
    float w3 = eb[(size_t)i3 * 8 + head] * m3;
    int s0 = __builtin_bit_cast(int, eb[(size_t)j  * 8 + 4]);
    int s1 = __builtin_bit_cast(int, eb[(size_t)i1 * 8 + 4]);
    int s2 = __builtin_bit_cast(int, eb[(size_t)i2 * 8 + 4]);
    int s3 = __builtin_bit_cast(int, eb[(size_t)i3 * 8 + 4]);
    uint4 v0 = h4[(size_t)s0 * 16 + l16];
    uint4 v1 = h4[(size_t)s1 * 16 + l16];
    uint4 v2 = h4[(size_t)s2 * 16 + l16];
    uint4 v3 = h4[(size_t)s3 * 16 + l16];
    wsum += w0 + w1 + w2 + w3;
    acc[0] += w0*bf_lo(v0.x) + w1*bf_lo(v1.x) + w2*bf_lo(v2.x) + w3*bf_lo(v3.x);
    acc[1] += w0*bf_hi(v0.x) + w1*bf_hi(v1.x) + w2*bf_hi(v2.x) + w3*bf_hi(v3.x);
    acc[2] += w0*bf_lo(v0.y) + w1*bf_lo(v1.y) + w2*bf_lo(v2.y) + w3*bf_lo(v3.y);
    acc[3] += w0*bf_hi(v0.y) + w1*bf_hi(v1.y) + w2*bf_hi(v2.y) + w3*bf_hi(v3.y);
    acc[4] += w0*bf_lo(v0.z) + w1*bf_lo(v1.z) + w2*bf_lo(v2.z) + w3*bf_lo(v3.z);
    acc[5] += w0*bf_hi(v0.z) + w1*bf_hi(v1.z) + w2*bf_hi(v2.z) + w3*bf_hi(v3.z);
    acc[6] += w0*bf_lo(v0.w) + w1*bf_lo(v1.w) + w2*bf_lo(v2.w) + w3*bf_lo(v3.w);
    acc[7] += w0*bf_hi(v0.w) + w1*bf_hi(v1.w) + w2*bf_hi(v2.w) + w3*bf_hi(v3.w);
  }

  float inv = 1.f / wsum;
  const float* bp = bias + l16 * 8;
  const float* fp = fcw  + l16 * 8;
  f32x4 b0 = *(const f32x4*)bp,      b1 = *(const f32x4*)(bp + 4);
  f32x4 f0 = *(const f32x4*)fp,      f1 = *(const f32x4*)(fp + 4);
  float p = 0.f;
  p += fmaxf(acc[0]*inv + b0[0], 0.f) * f0[0];
  p += fmaxf(acc[1]*inv + b0[1], 0.f) * f0[1];
  p += fmaxf(acc[2]*inv + b0[2], 0.f) * f0[2];
  p += fmaxf(acc[3]*inv + b0[3], 0.f) * f0[3];
  p += fmaxf(acc[4]*inv + b1[0], 0.f) * f1[0];
  p += fmaxf(acc[5]*inv + b1[1], 0.f) * f1[1];
  p += fmaxf(acc[6]*inv + b1[2], 0.f) * f1[2];
  p += fmaxf(acc[7]*inv + b1[3], 0.f) * f1[3];
  #pragma unroll
  for (int m = 1; m < 16; m <<= 1) p += __shfl_xor(p, m, 64);
  if (l16 == 0) out[node] = 1.f / (1.f + __expf(-(p + fcb[0])));
}

extern "C" void kernel_launch(void* const* d_in, const int* in_sizes, int n_in,
                              void* d_out, int out_size, void* d_ws, size_t ws_size,
                              hipStream_t stream) {
  const float* x    = (const float*)d_in[0];
  const int*   ei   = (const int*)  d_in[1];
  const float* W    = (const float*)d_in[2];
  const float* attS = (const float*)d_in[3];
  const float* attD = (const float*)d_in[4];
  const float* bias = (const float*)d_in[5];
  const float* fcw  = (const float*)d_in[6];
  const float* fcb  = (const float*)d_in[7];

  int N = in_sizes[0] / 128;
  int E = in_sizes[1] / 2;
  const int* srcA = ei;
  const int* dstA = ei + E;

  char* ws = (char*)d_ws;
  size_t off = 0;
  auto alloc = [&](size_t bytes) -> void* {
    void* p = ws + off;
    off += (bytes + 255) & ~(size_t)255;
    return p;
  };
  unsigned short* h  = (unsigned short*)alloc((size_t)N * 128 * 2);
  float* aS   = (float*)alloc((size_t)N * 4 * 4);
  float* aD   = (float*)alloc((size_t)N * 4 * 4);
  int* deg    = (int*)alloc((size_t)N * 4);
  int* rowptr = (int*)alloc(((size_t)N + 1) * 4);
  int* cursor = (int*)alloc((size_t)N * 4);
  float* eb   = (float*)alloc((size_t)E * 32 + 64);
  int* bsum   = (int*)alloc(4096);
  unsigned short* WbfT = (unsigned short*)alloc(128 * 136 * 2);

  int n4 = (N + 3) / 4;
  int ninit = (n4 > 16384) ? n4 : 16384;
  k_init<<<(ninit + 255) / 256, 256, 0, stream>>>(W, WbfT, (int4*)deg, n4);
  int nslices = (N + 15) / 16;
  int nbGemm = 512, nbHist = 256;   // best measured config
  k_gemm_hist<<<nbGemm + nbHist, 256, 0, stream>>>(x, WbfT, attS, attD, h, aS, aD,
                                                   N, nslices, nbGemm, dstA, E, deg);
  int nb = (N + 2047) / 2048;
  k_chunksum<<<nb, 256, 0, stream>>>(deg, N, bsum);
  if (nb <= 256){
    k_scanapply<<<nb, 256, 0, stream>>>(deg, bsum, nb, N, E, rowptr, cursor);
  } else {
    k_scansums<<<1, 256, 0, stream>>>(bsum, nb);
    k_scanfinal<<<nb, 256, 0, stream>>>(deg, bsum, N, E, rowptr, cursor);
  }
  k_scatter<<<(E + 255) / 256, 256, 0, stream>>>(srcA, dstA, E, cursor, aS, aD, eb);
  k_aggr<<<(N + 15) / 16, 256, 0, stream>>>((const uint4*)h, aS, aD, rowptr, eb,
                                            bias, fcw, fcb, (float*)d_out, N);
}